// Round 4
// baseline (498.081 us; speedup 1.0000x reference)
//
#include <hip/hip_runtime.h>

// SCF GRU layer: T=40, B=128, N=64, H=48, BN=8192, DIN=52.
// Round 4: identical to round 3 except the k_prep grid bug is fixed —
// loc sums need 5120 waves (1280 blocks x 4), round 3 launched only 320
// blocks so S[t>=10] was poison (absmax 0.116 on late timesteps).
// k_gru: weights pinned in VGPRs via empty inline-asm "+v" (R1 re-loaded
// them from L2 every step; R2 spilled 303MB to scratch), double-buffered
// LDS (1 barrier/step), register-prefetched x[t+1], packed fp32 FMA.

#define T_STEPS 40
#define BB      128
#define NN      64
#define HH      48
#define BN      8192

typedef float v2f __attribute__((ext_vector_type(2)));

__device__ __forceinline__ v2f pkfma(v2f a, v2f b, v2f c) {
    return __builtin_elementwise_fma(a, b, c);
}
__device__ __forceinline__ float sigmoid_(float x) {
    return __builtin_amdgcn_rcpf(1.0f + __expf(-x));
}

// ---- prep: blocks 0..1023 img mean (1 wave = 1 channel, no LDS/barrier);
//      blocks 1024..2303 loc sums (1 wave = 1 (t,b) pair, 1280 blocks x 4 waves = 5120).
__global__ __launch_bounds__(256) void k_prep(const float* __restrict__ f_img,
                                              const float* __restrict__ path,
                                              float* __restrict__ img_out,
                                              float* __restrict__ S) {
    const int wid  = threadIdx.x >> 6;
    const int lane = threadIdx.x & 63;
    if (blockIdx.x < 1024) {
        const int ch = blockIdx.x * 4 + wid;              // 0..4095 = b*32+c
        const float4* p = reinterpret_cast<const float4*>(f_img + (size_t)ch * 6400);
        float4 a = {0.f, 0.f, 0.f, 0.f};
#pragma unroll
        for (int i = 0; i < 25; ++i) {                    // 1600 float4 / 64 lanes
            const float4 v = p[lane + i * 64];
            a.x += v.x; a.y += v.y; a.z += v.z; a.w += v.w;
        }
        float s = (a.x + a.y) + (a.z + a.w);
        for (int off = 32; off > 0; off >>= 1) s += __shfl_down(s, off, 64);
        if (lane == 0) img_out[ch] = s * (1.0f / 6400.0f);
    } else {
        const int p = (blockIdx.x - 1024) * 4 + wid;      // t*128 + b, 0..5119
        if (p < T_STEPS * BB) {
            const float2 v = reinterpret_cast<const float2*>(path)[(size_t)p * 64 + lane];
            float sx = v.x, sy = v.y;
            for (int off = 32; off > 0; off >>= 1) {
                sx += __shfl_down(sx, off, 64);
                sy += __shfl_down(sy, off, 64);
            }
            if (lane == 0) { S[p * 2] = sx; S[p * 2 + 1] = sy; }
        }
    }
}

// ---- main recurrence: block = 192 threads = 2 rows x 96 (j in [0,48), half in {0,1}).
// Lane q = 2j+half, so shfl_xor(1) (DPP, cheap) pairs the two K-halves.
__global__ __launch_bounds__(192, 2) void k_gru(const float* __restrict__ path,
                                                const float* __restrict__ f_vel,
                                                const float* __restrict__ W_ih,
                                                const float* __restrict__ W_hh,
                                                const float* __restrict__ b_ih,
                                                const float* __restrict__ b_hh,
                                                const float* __restrict__ img,
                                                const float* __restrict__ S,
                                                float* __restrict__ out) {
    const int tid  = threadIdx.x;
    const int r    = tid / 96;
    const int q    = tid % 96;
    const int j    = q >> 1;
    const int half = q & 1;
    const int row  = blockIdx.x * 2 + r;
    const int b    = row >> 6;

    __shared__ __align__(16) float sh[2][2][HH];   // [buf][row][j]
    __shared__ __align__(16) float sx[2][2][20];   // [buf][row][loc2,rel2,vel16]

    // ---- weights into registers ----
    v2f wihr[5], wihz[5], wihn[5];
    v2f whhr[12], whhz[12], whhn[12];
    {
        const v2f* wr = reinterpret_cast<const v2f*>(W_ih + (j)      * 52 + half * 10);
        const v2f* wz = reinterpret_cast<const v2f*>(W_ih + (48 + j) * 52 + half * 10);
        const v2f* wn = reinterpret_cast<const v2f*>(W_ih + (96 + j) * 52 + half * 10);
#pragma unroll
        for (int p = 0; p < 5; ++p) { wihr[p] = wr[p]; wihz[p] = wz[p]; wihn[p] = wn[p]; }
    }
    {
        const v2f* wr = reinterpret_cast<const v2f*>(W_hh + (j)      * 48 + half * 24);
        const v2f* wz = reinterpret_cast<const v2f*>(W_hh + (48 + j) * 48 + half * 24);
        const v2f* wn = reinterpret_cast<const v2f*>(W_hh + (96 + j) * 48 + half * 24);
#pragma unroll
        for (int p = 0; p < 12; ++p) { whhr[p] = wr[p]; whhz[p] = wz[p]; whhn[p] = wn[p]; }
    }

    // ---- G0 = b_ih + img_feat . W_ih[:,20:52] (time-invariant gi part) ----
    float g0r, g0z, g0n;
    {
        const float4* im4 = reinterpret_cast<const float4*>(img + b * 32);
        const float4* wr4 = reinterpret_cast<const float4*>(W_ih + (j)      * 52 + 20);
        const float4* wz4 = reinterpret_cast<const float4*>(W_ih + (48 + j) * 52 + 20);
        const float4* wn4 = reinterpret_cast<const float4*>(W_ih + (96 + j) * 52 + 20);
        float ar = b_ih[j], az = b_ih[48 + j], an = b_ih[96 + j];
#pragma unroll
        for (int c = 0; c < 8; ++c) {
            const float4 iv = im4[c];
            const float4 a = wr4[c], z4 = wz4[c], n4 = wn4[c];
            ar = fmaf(iv.x, a.x, fmaf(iv.y, a.y, fmaf(iv.z, a.z, fmaf(iv.w, a.w, ar))));
            az = fmaf(iv.x, z4.x, fmaf(iv.y, z4.y, fmaf(iv.z, z4.z, fmaf(iv.w, z4.w, az))));
            an = fmaf(iv.x, n4.x, fmaf(iv.y, n4.y, fmaf(iv.z, n4.z, fmaf(iv.w, n4.w, an))));
        }
        g0r = ar; g0z = az; g0n = an;
    }
    // Accumulator seeds: half 0 carries (g0 + b_hh-where-applicable); the
    // butterfly sum then includes them exactly once.
    const float seedr = half ? 0.0f : g0r + b_hh[j];
    const float seedz = half ? 0.0f : g0z + b_hh[48 + j];
    const float seedn = half ? 0.0f : g0n;           // input-side n seed
    const float seedh = half ? 0.0f : b_hh[96 + j];  // hidden-side n seed (r multiplies)

    // ---- PIN weights in VGPRs: opaque to the allocator, cannot remat/spill-reload.
#pragma unroll
    for (int p = 0; p < 5; ++p) {
        asm volatile("" : "+v"(wihr[p]), "+v"(wihz[p]), "+v"(wihn[p]));
    }
#pragma unroll
    for (int p = 0; p < 12; ++p) {
        asm volatile("" : "+v"(whhr[p]), "+v"(whhz[p]), "+v"(whhn[p]));
    }

    // ---- preload x[0], h0 into buffer 0 ----
    float4 vreg;           // f_vel chunk (threads q<4)
    float2 preg, sreg;     // path + S (thread q==4)
    if (q < 4)  vreg = reinterpret_cast<const float4*>(f_vel + (size_t)row * 16)[q];
    if (q == 4) {
        preg = reinterpret_cast<const float2*>(path)[row];
        sreg = reinterpret_cast<const float2*>(S)[b];
    }
    if (half == 0) sh[0][r][j] = 0.0f;
    if (q < 4) reinterpret_cast<float4*>(&sx[0][r][4])[q] = vreg;
    if (q == 4) {
        sx[0][r][0] = preg.x;
        sx[0][r][1] = preg.y;
        sx[0][r][2] = (sreg.x - 64.0f * preg.x) * (1.0f / 63.0f);
        sx[0][r][3] = (sreg.y - 64.0f * preg.y) * (1.0f / 63.0f);
    }
    __syncthreads();

    int buf = 0;
    for (int t = 0; t < T_STEPS; ++t) {
        const int tn = (t + 1 < T_STEPS) ? t + 1 : t;
        if (q < 4)  vreg = reinterpret_cast<const float4*>(f_vel + ((size_t)tn * BN + row) * 16)[q];
        if (q == 4) {
            preg = reinterpret_cast<const float2*>(path)[(size_t)tn * BN + row];
            sreg = reinterpret_cast<const float2*>(S)[tn * BB + b];
        }

        const v2f* sx2 = reinterpret_cast<const v2f*>(&sx[buf][r][0]);
        const v2f* sh2 = reinterpret_cast<const v2f*>(&sh[buf][r][0]);
        v2f ar = {seedr, 0.f}, az = {seedz, 0.f}, ani = {seedn, 0.f}, anh = {seedh, 0.f};
#pragma unroll
        for (int p = 0; p < 5; ++p) {
            const v2f xv = sx2[half * 5 + p];
            ar  = pkfma(xv, wihr[p], ar);
            az  = pkfma(xv, wihz[p], az);
            ani = pkfma(xv, wihn[p], ani);
        }
#pragma unroll
        for (int p = 0; p < 12; ++p) {
            const v2f hv = sh2[half * 12 + p];
            ar  = pkfma(hv, whhr[p], ar);
            az  = pkfma(hv, whhz[p], az);
            anh = pkfma(hv, whhn[p], anh);
        }
        float sr  = ar.x + ar.y;   sr  += __shfl_xor(sr, 1, 64);
        float szv = az.x + az.y;   szv += __shfl_xor(szv, 1, 64);
        float sni = ani.x + ani.y; sni += __shfl_xor(sni, 1, 64);
        float snh = anh.x + anh.y; snh += __shfl_xor(snh, 1, 64);

        const float rg = sigmoid_(sr);
        const float zg = sigmoid_(szv);
        float a = sni + rg * snh;
        a = fminf(fmaxf(a, -15.0f), 15.0f);
        const float e = __expf(-2.0f * a);
        const float cand = (1.0f - e) * __builtin_amdgcn_rcpf(1.0f + e);
        const float hp = sh[buf][r][j];
        const float hn = zg * (hp - cand) + cand;

        const int nb = buf ^ 1;
        if (half == 0) sh[nb][r][j] = hn;
        else {
            out[((size_t)t * BN + row) * HH + j] = hn;
            if (t == T_STEPS - 1)
                out[(size_t)T_STEPS * BN * HH + (size_t)row * HH + j] = hn;
        }
        if (q < 4) reinterpret_cast<float4*>(&sx[nb][r][4])[q] = vreg;
        if (q == 4) {
            sx[nb][r][0] = preg.x;
            sx[nb][r][1] = preg.y;
            sx[nb][r][2] = (sreg.x - 64.0f * preg.x) * (1.0f / 63.0f);
            sx[nb][r][3] = (sreg.y - 64.0f * preg.y) * (1.0f / 63.0f);
        }
        __syncthreads();
        buf = nb;
    }
}

extern "C" void kernel_launch(void* const* d_in, const int* in_sizes, int n_in,
                              void* d_out, int out_size, void* d_ws, size_t ws_size,
                              hipStream_t stream) {
    const float* path  = (const float*)d_in[0];
    const float* f_vel = (const float*)d_in[1];
    const float* f_img = (const float*)d_in[2];
    const float* W_ih  = (const float*)d_in[3];
    const float* W_hh  = (const float*)d_in[4];
    const float* b_ih  = (const float*)d_in[5];
    const float* b_hh  = (const float*)d_in[6];
    float* out = (float*)d_out;

    float* ws  = (float*)d_ws;
    float* img = ws;            // 4096 floats
    float* S   = ws + 4096;     // 10240 floats

    hipLaunchKernelGGL(k_prep, dim3(1024 + 1280), dim3(256), 0, stream,
                       f_img, path, img, S);
    hipLaunchKernelGGL(k_gru, dim3(BN / 2), dim3(192), 0, stream,
                       path, f_vel, W_ih, W_hh, b_ih, b_hh, img, S, out);
}